// Round 13
// baseline (369.529 us; speedup 1.0000x reference)
//
#include <hip/hip_runtime.h>

typedef unsigned int   u32;
typedef unsigned short u16;
typedef __bf16 bf16x8 __attribute__((ext_vector_type(8)));
typedef float  f32x4  __attribute__((ext_vector_type(4)));

__device__ __forceinline__ u16 f2bf(float f) {
    u32 u = __builtin_bit_cast(u32, f);
    u += 0x7FFFu + ((u >> 16) & 1u);
    return (u16)(u >> 16);
}
// packed f32x2 -> bf16x2 (RNE), single instruction
__device__ __forceinline__ u32 cvtpk(float a, float b) {
    u32 r;
    asm("v_cvt_pk_bf16_f32 %0, %1, %2" : "=v"(r) : "v"(a), "v"(b));
    return r;
}
__device__ __forceinline__ bf16x8 ldfrag(const u16* p) {
    return __builtin_bit_cast(bf16x8, *reinterpret_cast<const uint4*>(p));
}

// bank-conflict swizzle on the 16B-chunk index (0..63): fold bits[5:3] into [2:0].
__device__ __forceinline__ u32 swz(u32 i) { return i ^ ((i >> 3) & 7u); }

// ---------------------------------------------------------------------------
// Fused Swin branch, R13 = R12 (swapped dataflow, best 156us/branch) made
// persistent: grid 256, 4 window-pairs per WG. The next pair's x (8 float4 /
// thread, SAME coalesced pattern as phase 1 -> no extra HBM traffic) is
// prefetched right after the phase3->4 barrier; liveness spans only phase 4
// (R9 lesson: long-liveness prefetch spilled; uncoalesced residual re-read
// quadrupled FETCH). Loads are consumed in next phase 1 before the first
// __syncthreads, so vmcnt-drain at barriers never stalls them.
// WG = 768 threads = 12 waves = TWO windows (balanced 3 waves/SIMD).
// Per-window LDS (u16, base=win*24576): [0,12288) yln 24 frag blocks
// (phase 3: wave w's blocks {s*6+w} = K scratch -> P(ks=1) -> O^T);
// [12288,24576) qreg 4 blocks/head (Q -> P(ks=0) -> V^T).
// ---------------------------------------------------------------------------
template<int SHIFT>
__global__ __launch_bounds__(768) void swin_branch(
    const float* __restrict__ xin, float* __restrict__ xout,
    const float* __restrict__ ln_g, const float* __restrict__ ln_b,
    const u16*   __restrict__ wqkv_t,  // [576][192] bf16 (pre-transposed)
    const float* __restrict__ qkv_b,   // [576]
    const u16*   __restrict__ wproj_t, // [192][192] bf16 (pre-transposed)
    const float* __restrict__ proj_b)  // [192]
{
    __shared__ __align__(16) u16 smem[49152];
    __shared__ float red1[2][6][64];
    __shared__ float red2[2][6][64];
    constexpr u32 QOFF = 12288;
    constexpr float QSC = 0.17677669529663689f * 1.4426950408889634f; // 1/sqrt(32)*log2(e)

    const int tid  = threadIdx.x;
    const int win  = (tid >= 384) ? 1 : 0;
    const int lt   = tid - win*384;
    const int wid  = lt >> 6;               // wave == head
    const int lane = lt & 63;
    const int lr   = lane & 15;
    const int lg   = lane >> 4;
    const u32 lsw  = swz((u32)lane);
    const u32 SB   = (u32)win * 24576u;

    const int ty = lane >> 3, tx = lane & 7;

    // prologue: load iteration-0 window x
    float4 xv4[8];
    {
        const int Wid = (int)blockIdx.x*2 + win;
        const int b0=Wid>>8, wy0=(Wid>>4)&15, wx0=Wid&15;
        const int shy=(wy0*8+ty+SHIFT)&127, shx=(wx0*8+tx+SHIFT)&127;
        const float* xp = xin + ((size_t)((b0*128+shy)*128+shx))*192 + wid*32;
        #pragma unroll
        for (int j=0;j<8;++j) xv4[j] = reinterpret_cast<const float4*>(xp)[j];
    }

    #pragma unroll 1
    for (int it = 0; it < 4; ++it) {
        const int Wid = (it*256 + (int)blockIdx.x)*2 + win;
        const int b   = Wid >> 8;
        const int wy  = (Wid >> 4) & 15;
        const int wx  = Wid & 15;

        // ---- Phase 1: LayerNorm from xv4 regs -> yln (frag layout) ----
        {
            float s1 = 0.f, s2 = 0.f;
            #pragma unroll
            for (int j = 0; j < 8; ++j) {
                float4 v = xv4[j];
                s1 += v.x+v.y+v.z+v.w;
                s2 += v.x*v.x + v.y*v.y + v.z*v.z + v.w*v.w;
            }
            red1[win][wid][lane] = s1; red2[win][wid][lane] = s2;
        }
        __syncthreads();   // also: prev iteration's proj reads of yln are done
        {
            float a1 = 0.f, a2 = 0.f;
            #pragma unroll
            for (int w = 0; w < 6; ++w) { a1 += red1[win][w][lane]; a2 += red2[win][w][lane]; }
            const float mu = a1 * (1.f/192.f);
            const float rs = rsqrtf(a2 * (1.f/192.f) - mu*mu + 1e-5f);
            const float* gp = ln_g + wid*32;
            const float* bp = ln_b + wid*32;
            const float* xf = reinterpret_cast<const float*>(xv4);
            const u32 yblk = SB + (u32)((lg*6 + wid)*512);
            #pragma unroll
            for (int cc8 = 0; cc8 < 4; ++cc8) {
                u32 pk[4];
                #pragma unroll
                for (int q = 0; q < 4; ++q) {
                    int j = cc8*8 + q*2;
                    float y0 = (xf[j]   - mu)*rs*gp[j]   + bp[j];
                    float y1 = (xf[j+1] - mu)*rs*gp[j+1] + bp[j+1];
                    pk[q] = cvtpk(y0, y1);
                }
                *reinterpret_cast<uint4*>(&smem[yblk + swz((u32)(lr + 16*cc8))*8]) =
                    make_uint4(pk[0],pk[1],pk[2],pk[3]);
            }
        }
        __syncthreads();

        // ---- Phase 2: QKV GEMM ----
        uint2 kpk[4][2];     // K^T packed bf16 (crosses barrier in regs)
        uint2 vpk[4][2];     // V  packed bf16 (crosses barrier in regs)
        {
            // pass 1 (SWAPPED): Q^T,K^T = mfma(W-frag, yln-frag)
            // D: lane holds X^T[d=16t+4lg+rg][token=16mi+lr]
            {
                f32x4 acc[4][4];
                #pragma unroll
                for (int mi=0; mi<4; ++mi)
                    #pragma unroll
                    for (int t=0; t<4; ++t) acc[mi][t] = f32x4{0.f,0.f,0.f,0.f};
                #pragma unroll
                for (int ks=0; ks<6; ++ks) {
                    bf16x8 af[4];
                    #pragma unroll
                    for (int mi=0; mi<4; ++mi)
                        af[mi] = ldfrag(&smem[SB + (u32)((mi*6+ks)*512) + lsw*8]);
                    bf16x8 bw[4];
                    #pragma unroll
                    for (int t=0; t<4; ++t)
                        bw[t] = ldfrag(&wqkv_t[((t>>1)*192 + wid*32 + (t&1)*16 + lr)*192 + 32*ks + 8*lg]);
                    #pragma unroll
                    for (int mi=0; mi<4; ++mi)
                        #pragma unroll
                        for (int t=0; t<4; ++t)
                            acc[mi][t] = __builtin_amdgcn_mfma_f32_16x16x32_bf16(bw[t], af[mi], acc[mi][t], 0,0,0);
                }
                // Q: bias + QSC scale -> qreg as B-frag (uint2 writes, wave-private)
                #pragma unroll
                for (int t=0; t<2; ++t) {
                    const float4 b4 = *reinterpret_cast<const float4*>(&qkv_b[wid*32 + t*16 + 4*lg]);
                    const u32 chunk = (u32)lr + 16u*(u32)(2*t + (lg>>1));
                    #pragma unroll
                    for (int mi=0; mi<4; ++mi) {
                        float v0 = (acc[mi][t][0] + b4.x) * QSC;
                        float v1 = (acc[mi][t][1] + b4.y) * QSC;
                        float v2 = (acc[mi][t][2] + b4.z) * QSC;
                        float v3 = (acc[mi][t][3] + b4.w) * QSC;
                        *reinterpret_cast<uint2*>(
                            &smem[SB + QOFF + (u32)(wid*2048) + mi*512 + swz(chunk)*8 + 4*(lg&1)]) =
                            make_uint2(cvtpk(v0,v1), cvtpk(v2,v3));
                    }
                }
                // K: bias -> kpk regs
                #pragma unroll
                for (int t2=0; t2<2; ++t2) {
                    const float4 b4 = *reinterpret_cast<const float4*>(&qkv_b[192 + wid*32 + t2*16 + 4*lg]);
                    #pragma unroll
                    for (int mi=0; mi<4; ++mi)
                        kpk[mi][t2] = make_uint2(
                            cvtpk(acc[mi][2+t2][0] + b4.x, acc[mi][2+t2][1] + b4.y),
                            cvtpk(acc[mi][2+t2][2] + b4.z, acc[mi][2+t2][3] + b4.w));
                }
            }
            // pass 2 (unswapped): V = mfma(yln, Wv); lane holds V[token=16mi+4lg+rg][d=16tv+lr]
            {
                f32x4 acc[4][2];
                #pragma unroll
                for (int mi=0; mi<4; ++mi)
                    #pragma unroll
                    for (int t=0; t<2; ++t) acc[mi][t] = f32x4{0.f,0.f,0.f,0.f};
                #pragma unroll
                for (int ks=0; ks<6; ++ks) {
                    bf16x8 af[4];
                    #pragma unroll
                    for (int mi=0; mi<4; ++mi)
                        af[mi] = ldfrag(&smem[SB + (u32)((mi*6+ks)*512) + lsw*8]);
                    bf16x8 bw[2];
                    #pragma unroll
                    for (int t=0; t<2; ++t)
                        bw[t] = ldfrag(&wqkv_t[(384 + wid*32 + t*16 + lr)*192 + 32*ks + 8*lg]);
                    #pragma unroll
                    for (int mi=0; mi<4; ++mi)
                        #pragma unroll
                        for (int t=0; t<2; ++t)
                            acc[mi][t] = __builtin_amdgcn_mfma_f32_16x16x32_bf16(af[mi], bw[t], acc[mi][t], 0,0,0);
                }
                #pragma unroll
                for (int tv=0; tv<2; ++tv) {
                    const float bias = qkv_b[384 + wid*32 + tv*16 + lr];
                    #pragma unroll
                    for (int mi=0; mi<4; ++mi)
                        vpk[mi][tv] = make_uint2(
                            cvtpk(acc[mi][tv][0] + bias, acc[mi][tv][1] + bias),
                            cvtpk(acc[mi][tv][2] + bias, acc[mi][tv][3] + bias));
                }
            }
        }
        __syncthreads();   // yln reads done -> wave w's blocks {s*6+w} become scratch

        // ---- Phase 3: attention (all-swapped, wave-local) ----
        float rsum[4];       // per q-col tile nq (q is lane-local on lr)
        f32x4 o_[2][4];      // O^T [dv][nq]
        {
            const u32 W  = SB + (u32)(wid*512);
            const u32 QB = SB + QOFF + (u32)(wid*2048);
            #define BLK(s) ((u32)(s)*3072u + W)

            // K scatter (A-frag): block mi, chunk = lr + 16*(2t2+(lg>>1))
            #pragma unroll
            for (int t2=0; t2<2; ++t2) {
                const u32 chunk = (u32)lr + 16u*(u32)(2*t2 + (lg>>1));
                #pragma unroll
                for (int mi=0; mi<4; ++mi)
                    *reinterpret_cast<uint2*>(
                        &smem[BLK(mi) + swz(chunk)*8 + 4*(lg&1)]) = kpk[mi][t2];
            }
            bf16x8 ak[4], bq[4];
            #pragma unroll
            for (int mi=0; mi<4; ++mi) ak[mi] = ldfrag(&smem[BLK(mi) + lsw*8]);
            #pragma unroll
            for (int nq=0; nq<4; ++nq) bq[nq] = ldfrag(&smem[QB + nq*512 + lsw*8]);
            __builtin_amdgcn_sched_barrier(0);

            // q-col classes (per nq; col qt = 16nq+lr)
            int qcl[4];
            if constexpr (SHIFT > 0) {
                #pragma unroll
                for (int nq=0; nq<4; ++nq) {
                    const int qt = 16*nq + lr;
                    const int hu = wy*8 + (qt>>3);
                    const int wu = wx*8 + (qt&7);
                    qcl[nq] = ((hu >= 124) ? 2 : (hu >= 120 ? 1 : 0))*3
                            + ((wu >= 124) ? 2 : (wu >= 120 ? 1 : 0));
                }
            }

            // S^T = mfma(K,Q); exp2 (q pre-scaled by log2e/sqrt(d)); zero-mask; pack
            uint2 p16[4][4];    // [mi][nq]
            #pragma unroll
            for (int mi=0; mi<4; ++mi) {
                f32x4 sr[4];
                #pragma unroll
                for (int nq=0; nq<4; ++nq)
                    sr[nq] = __builtin_amdgcn_mfma_f32_16x16x32_bf16(ak[mi], bq[nq],
                                 f32x4{0.f,0.f,0.f,0.f}, 0,0,0);
                #pragma unroll
                for (int rg=0; rg<4; ++rg) {
                    int kcl = 0;
                    if constexpr (SHIFT > 0) {
                        const int kt = 16*mi + 4*lg + rg;
                        const int hu = wy*8 + (kt>>3);
                        const int wu = wx*8 + (kt&7);
                        kcl = ((hu >= 124) ? 2 : (hu >= 120 ? 1 : 0))*3
                            + ((wu >= 124) ? 2 : (wu >= 120 ? 1 : 0));
                    }
                    #pragma unroll
                    for (int nq=0; nq<4; ++nq) {
                        float e = exp2f(sr[nq][rg]);
                        if constexpr (SHIFT > 0)
                            e = (kcl == qcl[nq]) ? e : 0.f;
                        sr[nq][rg] = e;
                    }
                }
                #pragma unroll
                for (int nq=0; nq<4; ++nq)
                    p16[mi][nq] = make_uint2(cvtpk(sr[nq][0], sr[nq][1]),
                                             cvtpk(sr[nq][2], sr[nq][3]));
            }

            // P^T scatter (B-frag): block(nq, ks=mi>>1): ks0 -> QB(nq), ks1 -> BLK(nq)
            #pragma unroll
            for (int mi=0; mi<4; ++mi) {
                const u32 chunk = (u32)lr + 16u*(u32)(2*(mi&1) + (lg>>1));
                #pragma unroll
                for (int nq=0; nq<4; ++nq) {
                    const u32 base = (mi >> 1) ? BLK(nq) : (QB + nq*512);
                    *reinterpret_cast<uint2*>(&smem[base + swz(chunk)*8 + 4*(lg&1)]) = p16[mi][nq];
                }
            }
            bf16x8 bp[4][2];
            #pragma unroll
            for (int nq=0; nq<4; ++nq) {
                bp[nq][0] = ldfrag(&smem[QB + nq*512 + lsw*8]);
                bp[nq][1] = ldfrag(&smem[BLK(nq) + lsw*8]);
            }
            __builtin_amdgcn_sched_barrier(0);

            // row sums per q-col via ones-MFMA on P^T B-frags
            bf16x8 aones;
            {
                const u32 one2 = 0x3F803F80u;
                aones = __builtin_bit_cast(bf16x8, make_uint4(one2, one2, one2, one2));
            }
            #pragma unroll
            for (int nq=0; nq<4; ++nq) {
                f32x4 racc = __builtin_amdgcn_mfma_f32_16x16x32_bf16(aones, bp[nq][0],
                                 f32x4{0.f,0.f,0.f,0.f}, 0,0,0);
                racc = __builtin_amdgcn_mfma_f32_16x16x32_bf16(aones, bp[nq][1], racc, 0,0,0);
                rsum[nq] = __builtin_amdgcn_rcpf(racc[0]);
            }

            // V^T scatter (A-frag) into QB blocks (P ks=0 dead after bp reads)
            #pragma unroll
            for (int mi=0; mi<4; ++mi) {
                const u32 chunk = (u32)lr + 16u*(u32)(2*(mi&1) + (lg>>1));
                #pragma unroll
                for (int tv=0; tv<2; ++tv)
                    *reinterpret_cast<uint2*>(
                        &smem[QB + (u32)((2*tv + (mi>>1))*512) + swz(chunk)*8 + 4*(lg&1)]) = vpk[mi][tv];
            }
            bf16x8 av[2][2];
            #pragma unroll
            for (int dv=0; dv<2; ++dv)
                #pragma unroll
                for (int ks=0; ks<2; ++ks)
                    av[dv][ks] = ldfrag(&smem[QB + (u32)((2*dv + ks)*512) + lsw*8]);
            __builtin_amdgcn_sched_barrier(0);

            // O^T = V^T * P^T
            #pragma unroll
            for (int dv=0; dv<2; ++dv)
                #pragma unroll
                for (int nq=0; nq<4; ++nq) {
                    o_[dv][nq] = __builtin_amdgcn_mfma_f32_16x16x32_bf16(av[dv][0], bp[nq][0],
                                     f32x4{0.f,0.f,0.f,0.f}, 0,0,0);
                    o_[dv][nq] = __builtin_amdgcn_mfma_f32_16x16x32_bf16(av[dv][1], bp[nq][1],
                                     o_[dv][nq], 0,0,0);
                }
            __builtin_amdgcn_sched_barrier(0);

            // normalized attn_out -> proj A-frag blocks BLK(nq) (uint2 writes)
            #pragma unroll
            for (int dv=0; dv<2; ++dv) {
                const u32 chunk = (u32)lr + 16u*(u32)(2*dv + (lg>>1));
                #pragma unroll
                for (int nq=0; nq<4; ++nq) {
                    const float r = rsum[nq];
                    *reinterpret_cast<uint2*>(&smem[BLK(nq) + swz(chunk)*8 + 4*(lg&1)]) =
                        make_uint2(cvtpk(o_[dv][nq][0]*r, o_[dv][nq][1]*r),
                                   cvtpk(o_[dv][nq][2]*r, o_[dv][nq][3]*r));
                }
            }
            #undef BLK
        }
        __syncthreads();

        // ---- x-prefetch for next iteration (short liveness: phase 4 only) ----
        if (it < 3) {
            const int WidN = ((it+1)*256 + (int)blockIdx.x)*2 + win;
            const int bn=WidN>>8, wyn=(WidN>>4)&15, wxn=WidN&15;
            const int shy=(wyn*8+ty+SHIFT)&127, shx=(wxn*8+tx+SHIFT)&127;
            const float* xp = xin + ((size_t)((bn*128+shy)*128+shx))*192 + wid*32;
            #pragma unroll
            for (int j=0;j<8;++j) xv4[j] = reinterpret_cast<const float4*>(xp)[j];
        }

        // ---- Phase 4: proj GEMM [64x192]@[192x192] + bias + residual ----
        {
            f32x4 a2[4][2];
            #pragma unroll
            for (int mi=0; mi<4; ++mi)
                #pragma unroll
                for (int ni=0; ni<2; ++ni) a2[mi][ni] = f32x4{0.f,0.f,0.f,0.f};
            #pragma unroll
            for (int ks=0; ks<6; ++ks) {
                bf16x8 af[4], bw[2];
                #pragma unroll
                for (int mi=0; mi<4; ++mi)
                    af[mi] = ldfrag(&smem[SB + (u32)((mi*6+ks)*512) + lsw*8]);
                #pragma unroll
                for (int ni=0; ni<2; ++ni)
                    bw[ni] = ldfrag(&wproj_t[(wid*32 + 16*ni + lr)*192 + 32*ks + 8*lg]);
                #pragma unroll
                for (int mi=0; mi<4; ++mi)
                    #pragma unroll
                    for (int ni=0; ni<2; ++ni)
                        a2[mi][ni] = __builtin_amdgcn_mfma_f32_16x16x32_bf16(af[mi], bw[ni], a2[mi][ni], 0,0,0);
            }
            #pragma unroll
            for (int ni=0; ni<2; ++ni) {
                const int c  = wid*32 + 16*ni + lr;
                const float pb = proj_b[c];
                #pragma unroll
                for (int mi=0; mi<4; ++mi)
                    #pragma unroll
                    for (int rg=0; rg<4; ++rg) {
                        const int row = 16*mi + 4*lg + rg;
                        const int ty2 = row >> 3, tx2 = row & 7;
                        const int shy = (wy*8 + ty2 + SHIFT) & 127;
                        const int shx = (wx*8 + tx2 + SHIFT) & 127;
                        const size_t idx = ((size_t)((b*128 + shy)*128 + shx))*192 + c;
                        xout[idx] = xin[idx] + a2[mi][ni][rg] + pb;
                    }
            }
        }
    }
}

// ws layout (u16): [0) wqkv1_t 110592 | 110592) wproj1_t 36864 | 147456) wqkv2_t 110592 | 258048) wproj2_t 36864
__global__ void prep_weights(const float* __restrict__ qkv1, const float* __restrict__ proj1,
                             const float* __restrict__ qkv2, const float* __restrict__ proj2,
                             u16* __restrict__ ws)
{
    const int i = blockIdx.x*blockDim.x + threadIdx.x;
    if (i < 110592) {
        const int n = i / 192, k = i - n*192;
        ws[i]          = f2bf(qkv1[k*576 + n]);
        ws[147456 + i] = f2bf(qkv2[k*576 + n]);
    }
    if (i < 36864) {
        const int n = i / 192, k = i - n*192;
        ws[110592 + i] = f2bf(proj1[k*192 + n]);
        ws[258048 + i] = f2bf(proj2[k*192 + n]);
    }
}

extern "C" void kernel_launch(void* const* d_in, const int* in_sizes, int n_in,
                              void* d_out, int out_size, void* d_ws, size_t ws_size,
                              hipStream_t stream)
{
    const float* x       = (const float*)d_in[0];
    const float* ln1_g   = (const float*)d_in[1];
    const float* ln1_b   = (const float*)d_in[2];
    const float* qkv1_w  = (const float*)d_in[3];
    const float* qkv1_b  = (const float*)d_in[4];
    const float* proj1_w = (const float*)d_in[5];
    const float* proj1_b = (const float*)d_in[6];
    const float* ln2_g   = (const float*)d_in[7];
    const float* ln2_b   = (const float*)d_in[8];
    const float* qkv2_w  = (const float*)d_in[9];
    const float* qkv2_b  = (const float*)d_in[10];
    const float* proj2_w = (const float*)d_in[11];
    const float* proj2_b = (const float*)d_in[12];
    float* out = (float*)d_out;
    u16*   wsp = (u16*)d_ws;

    prep_weights<<<dim3(432), dim3(256), 0, stream>>>(qkv1_w, proj1_w, qkv2_w, proj2_w, wsp);
    swin_branch<0><<<dim3(256), dim3(768), 0, stream>>>(x,   out, ln1_g, ln1_b,
                                                        wsp,        qkv1_b, wsp+110592, proj1_b);
    swin_branch<4><<<dim3(256), dim3(768), 0, stream>>>(out, out, ln2_g, ln2_b,
                                                        wsp+147456, qkv2_b, wsp+258048, proj2_b);
}